// Round 6
// baseline (474.213 us; speedup 1.0000x reference)
//
#include <hip/hip_runtime.h>
#include <math.h>

#define CIN   32
#define COUT  32
#define HH    256
#define WW    256
#define BB    16
#define SDIM  512

// conv tiling: block = 16 rows x 14 cols, 4 waves, all 32 couts
#define XT    14            // output cols per block
#define YT    16            // output rows per block
#define NXT   19            // ceil(256/14)
#define NTILE (16 * NXT)    // tiles per (b,co) = 304

typedef __attribute__((ext_vector_type(8))) short bf16x8;
typedef __attribute__((ext_vector_type(4))) float f32x4;

// ---------------- prep: s = style @ (mod_weight*mscale)^T + bias ----------------
__global__ __launch_bounds__(512) void prep_s_kernel(
    const float* __restrict__ style,
    const float* __restrict__ mod_weight,
    const float* __restrict__ mod_bias,
    float* __restrict__ s_out) {
    int t = threadIdx.x;            // t -> (b, ci)
    int b = t >> 5, ci = t & 31;
    const float mscale = 0.044194173824159216f;  // 1/sqrt(512)
    const float* st = style + b * SDIM;
    const float* mw = mod_weight + ci * SDIM;
    float acc = 0.f;
    for (int d = 0; d < SDIM; d += 4) {
        acc += st[d]   * mw[d]
             + st[d+1] * mw[d+1]
             + st[d+2] * mw[d+2]
             + st[d+3] * mw[d+3];
    }
    s_out[t] = acc * mscale + mod_bias[ci];
}

__device__ __forceinline__ unsigned bf16_rne_bits(float x) {
    unsigned u = __float_as_uint(x);
    return (u + 0x7fffu + ((u >> 16) & 1u)) >> 16;   // round-nearest-even bf16
}

// ---------------- prep: pack per-(b,window) modulated weights as bf16 hi/lo ------
// Layout: Wk[((b*9 + w)*2 + part)*1024 + co*32 + ci]  (ushort bf16 bits)
// A-frag read: lane l, co-frag f: 16B at co=(16f + (l&15)), ci = 8*(l>>4)..+7
__global__ __launch_bounds__(256) void prep_w_kernel(
    const float* __restrict__ weight,
    const float* __restrict__ s,
    unsigned short* __restrict__ Wk) {
    int idx = blockIdx.x * 256 + threadIdx.x;   // over 16*32*32*9 = 147456
    if (idx >= BB * COUT * CIN * 9) return;
    const float wscale = 0.05892556509887896f;  // 1/sqrt(32*3*3)
    int b  = idx / (COUT * CIN * 9);
    int r  = idx % (COUT * CIN * 9);
    int co = r / (CIN * 9);
    int r2 = r % (CIN * 9);
    int ci = r2 / 9;
    int w  = r2 % 9;
    float wm = wscale * weight[co * (CIN * 9) + ci * 9 + w] * s[b * CIN + ci];
    unsigned hb = bf16_rne_bits(wm);
    float hif = __uint_as_float(hb << 16);
    unsigned lb = bf16_rne_bits(wm - hif);
    int base = ((b * 9 + w) * 2) * 1024 + co * 32 + ci;
    Wk[base]        = (unsigned short)hb;   // part 0: hi
    Wk[base + 1024] = (unsigned short)lb;   // part 1: lo
}

// ---------------- MFMA conv: 9 shifted GEMMs, K=cin=32, bf16 3-term split --------
// grid (NXT, 16, BB), 256 threads (4 waves). Wave wv owns rows 4wv..4wv+3, 32 couts.
// LDS X layout per phase: row y (0..18) = 1024B: 16 u-slots x 64B; element (u, k):
//   byte = y*1024 + u*64 + (((k>>3) + (u>>1))&3)*16 + (k&7)*2   (swizzled, 2-way free)
__global__ __launch_bounds__(256, 3) void conv_mfma_kernel(
    const float* __restrict__ input,
    const unsigned short* __restrict__ Wk,
    float* __restrict__ out,
    float2* __restrict__ partials) {

    __shared__ __align__(16) unsigned short xlds[19 * 512]; // 19 rows x 1024B
    __shared__ float2 stats[4 * 32];

    const int tid = threadIdx.x;
    const int xt = blockIdx.x, yt = blockIdx.y, b = blockIdx.z;
    const int x0 = xt * XT, y0 = yt * YT;
    const int t  = tid & 15;          // px lane within fragment
    const int g  = (tid >> 4) & 3;    // k-octet group
    const int wv = tid >> 6;          // wave 0..3

    f32x4 acc[4][2];
    #pragma unroll
    for (int i = 0; i < 4; ++i)
        #pragma unroll
        for (int f = 0; f < 2; ++f)
            acc[i][f] = (f32x4){0.f, 0.f, 0.f, 0.f};

    const unsigned short* wbase = Wk + b * 9 * 2 * 1024;

    #pragma unroll 1
    for (int phase = 0; phase < 2; ++phase) {
        if (phase) __syncthreads();   // drain phase-0 reads before overwrite

        // ---- stage (phase 0: x_hi, phase 1: x_lo), 1152 tasks of 8 ci each ----
        #pragma unroll 1
        for (int it = 0; it < 5; ++it) {
            int idx = it * 256 + tid;
            if (idx < 1152) {
                int u = idx & 15, rest = idx >> 4;
                int gg = rest & 3, y = rest >> 2;          // y 0..17
                int gy = y0 - 1 + y, gx = x0 - 1 + u;
                bool ok = ((unsigned)gy < 256u) && ((unsigned)gx < 256u);
                const float* ip = input + ((b * 32 + gg * 8) * 65536) + gy * 256 + gx;
                unsigned short pk[8];
                #pragma unroll
                for (int j = 0; j < 8; ++j) {
                    float x = ok ? ip[j * 65536] : 0.f;
                    unsigned hb = bf16_rne_bits(x);
                    if (phase == 0) {
                        pk[j] = (unsigned short)hb;
                    } else {
                        float lo = x - __uint_as_float(hb << 16);
                        pk[j] = (unsigned short)bf16_rne_bits(lo);
                    }
                }
                int slot = (gg + (u >> 1)) & 3;
                *(bf16x8*)(&xlds[y * 512 + u * 32 + slot * 8]) = *(bf16x8*)pk;
            }
        }
        __syncthreads();

        // ---- 9 shifted GEMMs over this phase's X ----
        #pragma unroll
        for (int w9 = 0; w9 < 9; ++w9) {
            const int kh = w9 / 3, kw = w9 % 3;
            // clamp u for lanes whose output column is invalid (t >= XT):
            // they'd otherwise read past the 16 staged column-slots into
            // unwritten LDS (row 18) -> NaN garbage. Any staged column works;
            // their results are discarded via select below.
            const int u = (t < XT) ? (t + kw) : kw;
            const int slot = (g + (u >> 1)) & 3;
            bf16x8 xb[4];
            #pragma unroll
            for (int i = 0; i < 4; ++i)
                xb[i] = *(const bf16x8*)(
                    &xlds[(4 * wv + i + kh) * 512 + u * 32 + slot * 8]);

            const int laneoff = t * 32 + g * 8;
            bf16x8 wa0[2], wa1[2];
            #pragma unroll
            for (int f = 0; f < 2; ++f) {
                wa0[f] = *(const bf16x8*)(wbase + (w9 * 2 + 0) * 1024 + f * 512 + laneoff);
                if (phase == 0)
                    wa1[f] = *(const bf16x8*)(wbase + (w9 * 2 + 1) * 1024 + f * 512 + laneoff);
            }
            #pragma unroll
            for (int i = 0; i < 4; ++i)
                #pragma unroll
                for (int f = 0; f < 2; ++f) {
                    acc[i][f] = __builtin_amdgcn_mfma_f32_16x16x32_bf16(
                        wa0[f], xb[i], acc[i][f], 0, 0, 0);
                    if (phase == 0)
                        acc[i][f] = __builtin_amdgcn_mfma_f32_16x16x32_bf16(
                            wa1[f], xb[i], acc[i][f], 0, 0, 0);
                }
        }
    }

    // ---- stores + per-(b,co,tile) stats ----
    const bool valid = (t < XT) && (x0 + t < 256);
    float s_[2][4], q_[2][4];
    #pragma unroll
    for (int f = 0; f < 2; ++f)
        #pragma unroll
        for (int r = 0; r < 4; ++r) { s_[f][r] = 0.f; q_[f][r] = 0.f; }

    #pragma unroll
    for (int i = 0; i < 4; ++i) {
        const int gy = y0 + 4 * wv + i;
        #pragma unroll
        for (int f = 0; f < 2; ++f) {
            #pragma unroll
            for (int r = 0; r < 4; ++r) {
                float v = acc[i][f][r];
                if (valid)
                    out[(b * 32 + 16 * f + 4 * g + r) * 65536 + gy * 256 + x0 + t] = v;
                // select (not multiply) so garbage lanes can never poison stats
                float vs = valid ? v : 0.f;
                s_[f][r] += vs;
                q_[f][r] += vs * vs;
            }
        }
    }
    #pragma unroll
    for (int f = 0; f < 2; ++f)
        #pragma unroll
        for (int r = 0; r < 4; ++r) {
            #pragma unroll
            for (int off = 1; off < 16; off <<= 1) {
                s_[f][r] += __shfl_xor(s_[f][r], off);
                q_[f][r] += __shfl_xor(q_[f][r], off);
            }
        }
    if (t == 0) {
        #pragma unroll
        for (int f = 0; f < 2; ++f)
            #pragma unroll
            for (int r = 0; r < 4; ++r)
                stats[wv * 32 + 16 * f + 4 * g + r] = make_float2(s_[f][r], q_[f][r]);
    }
    __syncthreads();
    if (tid < 32) {
        float ss = 0.f, qq = 0.f;
        #pragma unroll
        for (int w = 0; w < 4; ++w) {
            float2 p = stats[w * 32 + tid];
            ss += p.x; qq += p.y;
        }
        partials[(b * 32 + tid) * NTILE + yt * NXT + xt] = make_float2(ss, qq);
    }
}

// ---------------- fold tile partials -> inv std ----------------
__global__ __launch_bounds__(256) void reduce_kernel(
    const float2* __restrict__ partials,
    float* __restrict__ inv_std) {
    int t = blockIdx.x * 256 + threadIdx.x;
    if (t >= BB * COUT) return;
    float s = 0.f, sq = 0.f;
    for (int k = 0; k < NTILE; ++k) {
        float2 p = partials[t * NTILE + k];
        s += p.x; sq += p.y;
    }
    const float N = 65536.f;
    float var = (sq - s * s / N) / (N - 1.f);   // unbiased (ddof=1)
    inv_std[t] = 1.0f / sqrtf(var);
}

// ---------------- scale output in place ----------------
__global__ __launch_bounds__(256) void scale_kernel(
    float4* __restrict__ out,
    const float* __restrict__ inv_std) {
    const int n4 = BB * COUT * HH * WW / 4;     // 8388608
    for (int i = blockIdx.x * 256 + threadIdx.x; i < n4; i += gridDim.x * 256) {
        float m = inv_std[i >> 14];
        float4 v = out[i];
        v.x *= m; v.y *= m; v.z *= m; v.w *= m;
        out[i] = v;
    }
}

extern "C" void kernel_launch(void* const* d_in, const int* in_sizes, int n_in,
                              void* d_out, int out_size, void* d_ws, size_t ws_size,
                              hipStream_t stream) {
    const float* input      = (const float*)d_in[0];
    const float* style      = (const float*)d_in[1];
    const float* weight     = (const float*)d_in[2];
    const float* mod_weight = (const float*)d_in[3];
    const float* mod_bias   = (const float*)d_in[4];
    float* out = (float*)d_out;
    char*  ws  = (char*)d_ws;

    float*          s        = (float*)ws;                       // 2048 B
    unsigned short* Wk       = (unsigned short*)(ws + 2048);     // 589824 B
    float2*         partials = (float2*)(ws + 2048 + 589824);    // 512*304*8 = 1245184 B
    float*          inv      = (float*)(ws + 2048 + 589824 + 1245184);

    prep_s_kernel<<<1, 512, 0, stream>>>(style, mod_weight, mod_bias, s);
    prep_w_kernel<<<(BB * COUT * CIN * 9 + 255) / 256, 256, 0, stream>>>(
        weight, s, Wk);

    dim3 grid(NXT, 16, BB);
    conv_mfma_kernel<<<grid, 256, 0, stream>>>(input, Wk, out, partials);

    reduce_kernel<<<2, 256, 0, stream>>>(partials, inv);
    scale_kernel<<<2048, 256, 0, stream>>>((float4*)out, inv);
}

// Round 7
// 245.820 us; speedup vs baseline: 1.9291x; 1.9291x over previous
//
#include <hip/hip_runtime.h>
#include <math.h>

#define CIN   32
#define COUT  32
#define HH    256
#define WW    256
#define BB    16
#define SDIM  512

#define XT    16
#define YT    16
#define NXT   16
#define NTILE 256           // 16x16 tiles per (b,co)

typedef __attribute__((ext_vector_type(8))) short bf16x8;
typedef __attribute__((ext_vector_type(4))) float f32x4;
typedef __attribute__((ext_vector_type(4))) unsigned short u16x4;

__device__ __forceinline__ unsigned bf16_rne_bits(float x) {
    unsigned u = __float_as_uint(x);
    return (u + 0x7fffu + ((u >> 16) & 1u)) >> 16;   // round-nearest-even bf16
}

// ---------------- prep: s = style @ (mod_weight*mscale)^T + bias ----------------
__global__ __launch_bounds__(512) void prep_s_kernel(
    const float* __restrict__ style,
    const float* __restrict__ mod_weight,
    const float* __restrict__ mod_bias,
    float* __restrict__ s_out) {
    int t = threadIdx.x;            // t -> (b, ci)
    int b = t >> 5, ci = t & 31;
    const float mscale = 0.044194173824159216f;  // 1/sqrt(512)
    const float* st = style + b * SDIM;
    const float* mw = mod_weight + ci * SDIM;
    float acc = 0.f;
    for (int d = 0; d < SDIM; d += 4) {
        acc += st[d]   * mw[d]
             + st[d+1] * mw[d+1]
             + st[d+2] * mw[d+2]
             + st[d+3] * mw[d+3];
    }
    s_out[t] = acc * mscale + mod_bias[ci];
}

// ---------------- prep: pack per-(b,window) modulated weights as bf16 hi/lo ------
// Layout: Wk[((b*9 + w)*2 + part)*1024 + co*32 + ci]  (ushort bf16 bits)
__global__ __launch_bounds__(256) void prep_w_kernel(
    const float* __restrict__ weight,
    const float* __restrict__ s,
    unsigned short* __restrict__ Wk) {
    int idx = blockIdx.x * 256 + threadIdx.x;   // over 16*32*32*9 = 147456
    if (idx >= BB * COUT * CIN * 9) return;
    const float wscale = 0.05892556509887896f;  // 1/sqrt(32*3*3)
    int b  = idx / (COUT * CIN * 9);
    int r  = idx % (COUT * CIN * 9);
    int co = r / (CIN * 9);
    int r2 = r % (CIN * 9);
    int ci = r2 / 9;
    int w  = r2 % 9;
    float wm = wscale * weight[co * (CIN * 9) + ci * 9 + w] * s[b * CIN + ci];
    unsigned hb = bf16_rne_bits(wm);
    float hif = __uint_as_float(hb << 16);
    unsigned lb = bf16_rne_bits(wm - hif);
    int base = ((b * 9 + w) * 2) * 1024 + co * 32 + ci;
    Wk[base]        = (unsigned short)hb;   // part 0: hi
    Wk[base + 1024] = (unsigned short)lb;   // part 1: lo
}

// ---------------- MFMA conv: 9 shifted GEMMs, K=cin=32 -------------------------
// X in bf16 (single term), W split hi/lo (2 terms). grid (16,16,16), 4 waves.
// Wave wv: co-half f=wv&1, y-rows rbase..rbase+7 (rbase=8*(wv>>1)).
// Stage A: fp32 gmem -> bf16 scratch[ci][y*24+x24] (float4 loads, 24 cols from x0-4)
// Stage B: repack -> xlds[y][u][k] (k-contiguous 16B per (y,u,part)).
__global__ __launch_bounds__(256, 3) void conv_mfma_kernel(
    const float* __restrict__ input,
    const unsigned short* __restrict__ Wk,
    float* __restrict__ out,
    float2* __restrict__ partials) {

    __shared__ __align__(16) unsigned short scratch[32 * 440]; // pad 432->440 (banks)
    __shared__ __align__(16) unsigned short xlds[18 * 18 * 32];
    __shared__ float2 stats[4 * 32];

    const int tid = threadIdx.x;
    const int xt = blockIdx.x, yt = blockIdx.y, b = blockIdx.z;
    const int x0 = xt * XT, y0 = yt * YT;
    const int t  = tid & 15;
    const int g  = (tid >> 4) & 3;
    const int wv = tid >> 6;
    const int f  = wv & 1;
    const int rbase = 8 * (wv >> 1);

    // ---- hoist all 18 weight fragments into registers (L2-resident) ----
    bf16x8 wa[9][2];
    {
        const unsigned short* wb =
            Wk + (b * 9 * 2) * 1024 + f * 512 + t * 32 + g * 8;
        #pragma unroll
        for (int w9 = 0; w9 < 9; ++w9) {
            wa[w9][0] = *(const bf16x8*)(wb + (2 * w9) * 1024);
            wa[w9][1] = *(const bf16x8*)(wb + (2 * w9 + 1) * 1024);
        }
    }

    // ---- stage A: 3456 float4 tasks (32ci x 18y x 6 xgroups) ----
    #pragma unroll
    for (int it = 0; it < 14; ++it) {
        int idx = it * 256 + tid;
        if (idx < 3456) {
            int xg   = idx % 6;
            int rest = idx / 6;
            int y    = rest % 18;
            int ci   = rest / 18;
            int gy  = y0 - 1 + y;
            int gx0 = x0 - 4 + 4 * xg;
            float4 v = make_float4(0.f, 0.f, 0.f, 0.f);
            if ((unsigned)gy < 256u && (unsigned)gx0 <= 252u)
                v = *(const float4*)&input[((b * 32 + ci) * 256 + gy) * 256 + gx0];
            u16x4 pk;
            pk.x = (unsigned short)bf16_rne_bits(v.x);
            pk.y = (unsigned short)bf16_rne_bits(v.y);
            pk.z = (unsigned short)bf16_rne_bits(v.z);
            pk.w = (unsigned short)bf16_rne_bits(v.w);
            *(u16x4*)&scratch[ci * 440 + y * 24 + xg * 4] = pk;
        }
    }
    __syncthreads();

    // ---- stage B: repack 1296 tasks (18y x 18u x 4 parts) ----
    #pragma unroll
    for (int it = 0; it < 6; ++it) {
        int idx = it * 256 + tid;
        if (idx < 1296) {
            int part = idx & 3;
            int s2   = idx >> 2;           // 0..323
            int u    = s2 % 18;
            int y    = s2 / 18;
            unsigned short pk[8];
            #pragma unroll
            for (int j = 0; j < 8; ++j)
                pk[j] = scratch[(part * 8 + j) * 440 + y * 24 + (u + 3)];
            *(bf16x8*)&xlds[(y * 18 + u) * 32 + part * 8] = *(bf16x8*)pk;
        }
    }
    __syncthreads();

    // ---- compute: 9 windows x 8 rows x 2 weight terms ----
    f32x4 acc[8];
    #pragma unroll
    for (int i = 0; i < 8; ++i) acc[i] = (f32x4){0.f, 0.f, 0.f, 0.f};

    #pragma unroll
    for (int w9 = 0; w9 < 9; ++w9) {
        const int kh = w9 / 3, kw = w9 % 3;
        const int ubyte = (t + kw) * 64 + g * 16;
        #pragma unroll
        for (int i = 0; i < 8; ++i) {
            const int y = rbase + i + kh;
            bf16x8 xb = *(const bf16x8*)((const char*)xlds + y * 1152 + ubyte);
            acc[i] = __builtin_amdgcn_mfma_f32_16x16x32_bf16(
                wa[w9][0], xb, acc[i], 0, 0, 0);
            acc[i] = __builtin_amdgcn_mfma_f32_16x16x32_bf16(
                wa[w9][1], xb, acc[i], 0, 0, 0);
        }
    }

    // ---- epilogue: aligned 64B-line stores + stats ----
    float s_[4] = {0.f, 0.f, 0.f, 0.f}, q_[4] = {0.f, 0.f, 0.f, 0.f};
    #pragma unroll
    for (int i = 0; i < 8; ++i) {
        const int gy = y0 + rbase + i;
        #pragma unroll
        for (int r = 0; r < 4; ++r) {
            float v = acc[i][r];
            out[(b * 32 + 16 * f + 4 * g + r) * 65536 + gy * 256 + x0 + t] = v;
            s_[r] += v;
            q_[r] += v * v;
        }
    }
    #pragma unroll
    for (int r = 0; r < 4; ++r) {
        #pragma unroll
        for (int off = 1; off < 16; off <<= 1) {
            s_[r] += __shfl_xor(s_[r], off);
            q_[r] += __shfl_xor(q_[r], off);
        }
    }
    if (t == 0) {
        #pragma unroll
        for (int r = 0; r < 4; ++r)
            stats[wv * 32 + 16 * f + 4 * g + r] = make_float2(s_[r], q_[r]);
    }
    __syncthreads();
    if (tid < 32) {
        int w0 = (tid < 16) ? 0 : 1;            // waves 0/2 own co<16, 1/3 co>=16
        float2 a = stats[w0 * 32 + tid];
        float2 c = stats[(w0 + 2) * 32 + tid];
        partials[(b * 32 + tid) * NTILE + yt * NXT + xt] =
            make_float2(a.x + c.x, a.y + c.y);
    }
}

// ---------------- fold tile partials -> inv std ----------------
__global__ __launch_bounds__(256) void reduce_kernel(
    const float2* __restrict__ partials,
    float* __restrict__ inv_std) {
    int t = blockIdx.x * 256 + threadIdx.x;
    if (t >= BB * COUT) return;
    float s = 0.f, sq = 0.f;
    for (int k = 0; k < NTILE; ++k) {
        float2 p = partials[t * NTILE + k];
        s += p.x; sq += p.y;
    }
    const float N = 65536.f;
    float var = (sq - s * s / N) / (N - 1.f);   // unbiased (ddof=1)
    inv_std[t] = 1.0f / sqrtf(var);
}

// ---------------- scale output in place ----------------
__global__ __launch_bounds__(256) void scale_kernel(
    float4* __restrict__ out,
    const float* __restrict__ inv_std) {
    const int n4 = BB * COUT * HH * WW / 4;     // 8388608
    for (int i = blockIdx.x * 256 + threadIdx.x; i < n4; i += gridDim.x * 256) {
        float m = inv_std[i >> 14];
        float4 v = out[i];
        v.x *= m; v.y *= m; v.z *= m; v.w *= m;
        out[i] = v;
    }
}

extern "C" void kernel_launch(void* const* d_in, const int* in_sizes, int n_in,
                              void* d_out, int out_size, void* d_ws, size_t ws_size,
                              hipStream_t stream) {
    const float* input      = (const float*)d_in[0];
    const float* style      = (const float*)d_in[1];
    const float* weight     = (const float*)d_in[2];
    const float* mod_weight = (const float*)d_in[3];
    const float* mod_bias   = (const float*)d_in[4];
    float* out = (float*)d_out;
    char*  ws  = (char*)d_ws;

    float*          s        = (float*)ws;                        // 2048 B
    unsigned short* Wk       = (unsigned short*)(ws + 2048);      // 589824 B
    float2*         partials = (float2*)(ws + 2048 + 589824);     // 512*256*8 = 1048576 B
    float*          inv      = (float*)(ws + 2048 + 589824 + 1048576);

    prep_s_kernel<<<1, 512, 0, stream>>>(style, mod_weight, mod_bias, s);
    prep_w_kernel<<<(BB * COUT * CIN * 9 + 255) / 256, 256, 0, stream>>>(
        weight, s, Wk);

    dim3 grid(NXT, 16, BB);
    conv_mfma_kernel<<<grid, 256, 0, stream>>>(input, Wk, out, partials);

    reduce_kernel<<<2, 256, 0, stream>>>(partials, inv);
    scale_kernel<<<2048, 256, 0, stream>>>((float4*)out, inv);
}

// Round 8
// 185.184 us; speedup vs baseline: 2.5608x; 1.3274x over previous
//
#include <hip/hip_runtime.h>
#include <math.h>

#define CIN   32
#define COUT  32
#define HH    256
#define WW    256
#define BB    16
#define SDIM  512

#define XT    16
#define YT    16
#define NXT   16
#define NTILE 256           // 16x16 tiles per (b,co)
#define SCR_STRIDE 444      // scratch row pitch (ushorts): 888B, 8B-aligned, bank-spread

typedef __attribute__((ext_vector_type(8))) short bf16x8;
typedef __attribute__((ext_vector_type(4))) float f32x4;
typedef __attribute__((ext_vector_type(4))) unsigned short u16x4;

__device__ __forceinline__ unsigned bf16_rne_bits(float x) {
    unsigned u = __float_as_uint(x);
    return (u + 0x7fffu + ((u >> 16) & 1u)) >> 16;   // round-nearest-even bf16
}

// ---------------- prep: s = style @ (mod_weight*mscale)^T + bias ----------------
__global__ __launch_bounds__(512) void prep_s_kernel(
    const float* __restrict__ style,
    const float* __restrict__ mod_weight,
    const float* __restrict__ mod_bias,
    float* __restrict__ s_out) {
    int t = threadIdx.x;            // t -> (b, ci)
    int b = t >> 5, ci = t & 31;
    const float mscale = 0.044194173824159216f;  // 1/sqrt(512)
    const float* st = style + b * SDIM;
    const float* mw = mod_weight + ci * SDIM;
    float acc = 0.f;
    for (int d = 0; d < SDIM; d += 4) {
        acc += st[d]   * mw[d]
             + st[d+1] * mw[d+1]
             + st[d+2] * mw[d+2]
             + st[d+3] * mw[d+3];
    }
    s_out[t] = acc * mscale + mod_bias[ci];
}

// ---------------- prep: pack per-(b,window) modulated weights as bf16 hi/lo ------
// Layout: Wk[((b*9 + w)*2 + part)*1024 + co*32 + ci]  (ushort bf16 bits)
__global__ __launch_bounds__(256) void prep_w_kernel(
    const float* __restrict__ weight,
    const float* __restrict__ s,
    unsigned short* __restrict__ Wk) {
    int idx = blockIdx.x * 256 + threadIdx.x;   // over 16*32*32*9 = 147456
    if (idx >= BB * COUT * CIN * 9) return;
    const float wscale = 0.05892556509887896f;  // 1/sqrt(32*3*3)
    int b  = idx / (COUT * CIN * 9);
    int r  = idx % (COUT * CIN * 9);
    int co = r / (CIN * 9);
    int r2 = r % (CIN * 9);
    int ci = r2 / 9;
    int w  = r2 % 9;
    float wm = wscale * weight[co * (CIN * 9) + ci * 9 + w] * s[b * CIN + ci];
    unsigned hb = bf16_rne_bits(wm);
    float hif = __uint_as_float(hb << 16);
    unsigned lb = bf16_rne_bits(wm - hif);
    int base = ((b * 9 + w) * 2) * 1024 + co * 32 + ci;
    Wk[base]        = (unsigned short)hb;   // part 0: hi
    Wk[base + 1024] = (unsigned short)lb;   // part 1: lo
}

// ---------------- MFMA conv: 3 kw-passes of 3 shifted GEMMs --------------------
// grid 4096 (XCD-swizzled), 4 waves. Wave wv: co-half f=wv&1, rows rbase..+7.
// xlds entry (y,u): 64B, octet part at slot (part+(u>>1))&3  -> 2-way (free) reads.
__global__ __launch_bounds__(256, 3) void conv_mfma_kernel(
    const float* __restrict__ input,
    const unsigned short* __restrict__ Wk,
    float* __restrict__ out,
    float2* __restrict__ partials) {

    __shared__ __align__(16) unsigned short scratch[32 * SCR_STRIDE];
    __shared__ __align__(16) unsigned short xlds[18 * 18 * 32];
    __shared__ float2 stats[4 * 32];

    const int tid = threadIdx.x;
    // bijective XCD swizzle: each XCD gets 512 consecutive sw ids (2 b-slices)
    const int wg = blockIdx.x;
    const int sw = (wg & 7) * 512 + (wg >> 3);
    const int b  = sw >> 8;
    const int yt = (sw >> 4) & 15;
    const int xt = sw & 15;

    const int x0 = xt * XT, y0 = yt * YT;
    const int t  = tid & 15;
    const int g  = (tid >> 4) & 3;
    const int wv = tid >> 6;
    const int f  = wv & 1;
    const int rbase = 8 * (wv >> 1);

    // ---- stage A: 3456 float4 tasks (32ci x 18y x 6 xgroups) -> bf16 scratch ----
    #pragma unroll
    for (int it = 0; it < 14; ++it) {
        int idx = it * 256 + tid;
        if (idx < 3456) {
            int xg   = idx % 6;
            int rest = idx / 6;
            int y    = rest % 18;
            int ci   = rest / 18;
            int gy  = y0 - 1 + y;
            int gx0 = x0 - 4 + 4 * xg;
            float4 v = make_float4(0.f, 0.f, 0.f, 0.f);
            if ((unsigned)gy < 256u && (unsigned)gx0 <= 252u)
                v = *(const float4*)&input[((b * 32 + ci) * 256 + gy) * 256 + gx0];
            u16x4 pk;
            pk.x = (unsigned short)bf16_rne_bits(v.x);
            pk.y = (unsigned short)bf16_rne_bits(v.y);
            pk.z = (unsigned short)bf16_rne_bits(v.z);
            pk.w = (unsigned short)bf16_rne_bits(v.w);
            *(u16x4*)&scratch[ci * SCR_STRIDE + y * 24 + xg * 4] = pk;
        }
    }
    __syncthreads();

    // ---- stage B: repack 1296 tasks (18y x 18u x 4 parts), swizzled slots ----
    #pragma unroll
    for (int it = 0; it < 6; ++it) {
        int idx = it * 256 + tid;
        if (idx < 1296) {
            int part = idx & 3;
            int s2   = idx >> 2;           // 0..323
            int u    = s2 % 18;
            int y    = s2 / 18;
            unsigned short pk[8];
            #pragma unroll
            for (int j = 0; j < 8; ++j)
                pk[j] = scratch[(part * 8 + j) * SCR_STRIDE + y * 24 + (u + 3)];
            int slot = (part + (u >> 1)) & 3;
            *(bf16x8*)&xlds[(y * 18 + u) * 32 + slot * 8] = *(bf16x8*)pk;
        }
    }
    __syncthreads();

    // ---- compute: 3 kw-passes, each {6 weight frags, 10 row frags, 48 MFMA} ----
    f32x4 acc[8];
    #pragma unroll
    for (int i = 0; i < 8; ++i) acc[i] = (f32x4){0.f, 0.f, 0.f, 0.f};

    #pragma unroll 1
    for (int kw = 0; kw < 3; ++kw) {
        const int u = t + kw;                    // 0..17, always staged
        const int slot = (g + (u >> 1)) & 3;

        // weight fragments for windows kh*3+kw (issued first; L2 latency hides
        // under the ds_reads below)
        bf16x8 wf[3][2];
        const unsigned short* wb =
            Wk + (b * 9 * 2) * 1024 + f * 512 + t * 32 + g * 8;
        #pragma unroll
        for (int kh = 0; kh < 3; ++kh) {
            wf[kh][0] = *(const bf16x8*)(wb + ((kh * 3 + kw) * 2 + 0) * 1024);
            wf[kh][1] = *(const bf16x8*)(wb + ((kh * 3 + kw) * 2 + 1) * 1024);
        }

        // 10 input-row fragments (conflict-free swizzled ds_read_b128)
        bf16x8 xv[10];
        #pragma unroll
        for (int y = 0; y < 10; ++y)
            xv[y] = *(const bf16x8*)&xlds[((rbase + y) * 18 + u) * 32 + slot * 8];

        #pragma unroll
        for (int kh = 0; kh < 3; ++kh)
            #pragma unroll
            for (int i = 0; i < 8; ++i) {
                acc[i] = __builtin_amdgcn_mfma_f32_16x16x32_bf16(
                    wf[kh][0], xv[i + kh], acc[i], 0, 0, 0);
                acc[i] = __builtin_amdgcn_mfma_f32_16x16x32_bf16(
                    wf[kh][1], xv[i + kh], acc[i], 0, 0, 0);
            }
    }

    // ---- epilogue: stores + stats ----
    float s_[4] = {0.f, 0.f, 0.f, 0.f}, q_[4] = {0.f, 0.f, 0.f, 0.f};
    #pragma unroll
    for (int i = 0; i < 8; ++i) {
        const int gy = y0 + rbase + i;
        #pragma unroll
        for (int r = 0; r < 4; ++r) {
            float v = acc[i][r];
            out[(b * 32 + 16 * f + 4 * g + r) * 65536 + gy * 256 + x0 + t] = v;
            s_[r] += v;
            q_[r] += v * v;
        }
    }
    #pragma unroll
    for (int r = 0; r < 4; ++r) {
        #pragma unroll
        for (int off = 1; off < 16; off <<= 1) {
            s_[r] += __shfl_xor(s_[r], off);
            q_[r] += __shfl_xor(q_[r], off);
        }
    }
    if (t == 0) {
        #pragma unroll
        for (int r = 0; r < 4; ++r)
            stats[wv * 32 + 16 * f + 4 * g + r] = make_float2(s_[r], q_[r]);
    }
    __syncthreads();
    if (tid < 32) {
        int w0 = (tid < 16) ? 0 : 1;            // waves 0/2 own co<16, 1/3 co>=16
        float2 a = stats[w0 * 32 + tid];
        float2 c = stats[(w0 + 2) * 32 + tid];
        partials[(b * 32 + tid) * NTILE + yt * NXT + xt] =
            make_float2(a.x + c.x, a.y + c.y);
    }
}

// ---------------- fold tile partials -> inv std ----------------
__global__ __launch_bounds__(256) void reduce_kernel(
    const float2* __restrict__ partials,
    float* __restrict__ inv_std) {
    int t = blockIdx.x * 256 + threadIdx.x;
    if (t >= BB * COUT) return;
    float s = 0.f, sq = 0.f;
    for (int k = 0; k < NTILE; ++k) {
        float2 p = partials[t * NTILE + k];
        s += p.x; sq += p.y;
    }
    const float N = 65536.f;
    float var = (sq - s * s / N) / (N - 1.f);   // unbiased (ddof=1)
    inv_std[t] = 1.0f / sqrtf(var);
}

// ---------------- scale output in place ----------------
__global__ __launch_bounds__(256) void scale_kernel(
    float4* __restrict__ out,
    const float* __restrict__ inv_std) {
    const int n4 = BB * COUT * HH * WW / 4;     // 8388608
    for (int i = blockIdx.x * 256 + threadIdx.x; i < n4; i += gridDim.x * 256) {
        float m = inv_std[i >> 14];
        float4 v = out[i];
        v.x *= m; v.y *= m; v.z *= m; v.w *= m;
        out[i] = v;
    }
}

extern "C" void kernel_launch(void* const* d_in, const int* in_sizes, int n_in,
                              void* d_out, int out_size, void* d_ws, size_t ws_size,
                              hipStream_t stream) {
    const float* input      = (const float*)d_in[0];
    const float* style      = (const float*)d_in[1];
    const float* weight     = (const float*)d_in[2];
    const float* mod_weight = (const float*)d_in[3];
    const float* mod_bias   = (const float*)d_in[4];
    float* out = (float*)d_out;
    char*  ws  = (char*)d_ws;

    float*          s        = (float*)ws;                        // 2048 B
    unsigned short* Wk       = (unsigned short*)(ws + 2048);      // 589824 B
    float2*         partials = (float2*)(ws + 2048 + 589824);     // 1048576 B
    float*          inv      = (float*)(ws + 2048 + 589824 + 1048576);

    prep_s_kernel<<<1, 512, 0, stream>>>(style, mod_weight, mod_bias, s);
    prep_w_kernel<<<(BB * COUT * CIN * 9 + 255) / 256, 256, 0, stream>>>(
        weight, s, Wk);

    conv_mfma_kernel<<<4096, 256, 0, stream>>>(input, Wk, out, partials);

    reduce_kernel<<<2, 256, 0, stream>>>(partials, inv);
    scale_kernel<<<2048, 256, 0, stream>>>((float4*)out, inv);
}

// Round 9
// 181.939 us; speedup vs baseline: 2.6064x; 1.0178x over previous
//
#include <hip/hip_runtime.h>
#include <math.h>

#define CIN   32
#define COUT  32
#define HH    256
#define WW    256
#define BB    16
#define SDIM  512

#define XT    16
#define YT    16
#define NXT   16
#define NTILE 256           // 16x16 tiles per (b,co)
#define YS    584           // xlds row stride (ushorts): 1168B = 16B-aligned, +4 banks/row

typedef __attribute__((ext_vector_type(8))) short bf16x8;
typedef __attribute__((ext_vector_type(4))) float f32x4;
typedef __attribute__((ext_vector_type(8))) unsigned short u16x8;

__device__ __forceinline__ unsigned bf16_rne_bits(float x) {
    unsigned u = __float_as_uint(x);
    return (u + 0x7fffu + ((u >> 16) & 1u)) >> 16;   // round-nearest-even bf16
}

// ---------------- prep: s = style @ (mod_weight*mscale)^T + bias ----------------
__global__ __launch_bounds__(512) void prep_s_kernel(
    const float* __restrict__ style,
    const float* __restrict__ mod_weight,
    const float* __restrict__ mod_bias,
    float* __restrict__ s_out) {
    int t = threadIdx.x;            // t -> (b, ci)
    int b = t >> 5, ci = t & 31;
    const float mscale = 0.044194173824159216f;  // 1/sqrt(512)
    const float* st = style + b * SDIM;
    const float* mw = mod_weight + ci * SDIM;
    float acc = 0.f;
    for (int d = 0; d < SDIM; d += 4) {
        acc += st[d]   * mw[d]
             + st[d+1] * mw[d+1]
             + st[d+2] * mw[d+2]
             + st[d+3] * mw[d+3];
    }
    s_out[t] = acc * mscale + mod_bias[ci];
}

// ---------------- prep: pack per-(b,window) modulated weights as bf16 hi/lo ------
// Layout: Wk[((b*9 + w)*2 + part)*1024 + co*32 + ci]  (ushort bf16 bits)
__global__ __launch_bounds__(256) void prep_w_kernel(
    const float* __restrict__ weight,
    const float* __restrict__ s,
    unsigned short* __restrict__ Wk) {
    int idx = blockIdx.x * 256 + threadIdx.x;   // over 16*32*32*9 = 147456
    if (idx >= BB * COUT * CIN * 9) return;
    const float wscale = 0.05892556509887896f;  // 1/sqrt(32*3*3)
    int b  = idx / (COUT * CIN * 9);
    int r  = idx % (COUT * CIN * 9);
    int co = r / (CIN * 9);
    int r2 = r % (CIN * 9);
    int ci = r2 / 9;
    int w  = r2 % 9;
    float wm = wscale * weight[co * (CIN * 9) + ci * 9 + w] * s[b * CIN + ci];
    unsigned hb = bf16_rne_bits(wm);
    float hif = __uint_as_float(hb << 16);
    unsigned lb = bf16_rne_bits(wm - hif);
    int base = ((b * 9 + w) * 2) * 1024 + co * 32 + ci;
    Wk[base]        = (unsigned short)hb;   // part 0: hi
    Wk[base + 1024] = (unsigned short)lb;   // part 1: lo
}

// ---------------- MFMA conv: fused transpose-on-write staging ------------------
// grid 4096 (XCD-swizzled), 4 waves, 6 blocks/CU (22KB LDS).
// xlds elem(y,u,ci) = y*YS + u*32 + (((ci>>3)+(u>>1))&3)*8 + (ci&7)
//   -> compute ds_read_b128 2-way max (free); staging writes scalar u16.
__global__ __launch_bounds__(256, 6) void conv_mfma_kernel(
    const float* __restrict__ input,
    const unsigned short* __restrict__ Wk,
    float* __restrict__ out,
    unsigned short* __restrict__ bfout,    // null -> fp32 path
    float2* __restrict__ partials) {

    __shared__ __align__(16) unsigned short xlds[18 * YS];
    __shared__ float2 stats[4 * 32];

    const int tid = threadIdx.x;
    // bijective XCD swizzle: each XCD gets 512 consecutive sw ids (2 b-slices)
    const int wg = blockIdx.x;
    const int sw = (wg & 7) * 512 + (wg >> 3);
    const int b  = sw >> 8;
    const int yt = (sw >> 4) & 15;
    const int xt = sw & 15;

    const int x0 = xt * XT, y0 = yt * YT;
    const int t  = tid & 15;
    const int g  = (tid >> 4) & 3;
    const int wv = tid >> 6;
    const int f  = wv & 1;
    const int rbase = 8 * (wv >> 1);

    // ---- fused staging: 3456 tasks (32ci x 18y x 6 xgroups), direct to xlds ----
    #pragma unroll
    for (int it = 0; it < 14; ++it) {
        int idx = it * 256 + tid;
        if (idx < 3456) {
            int xg   = idx % 6;
            int rest = idx / 6;
            int y    = rest % 18;
            int ci   = rest / 18;
            int gy  = y0 - 1 + y;
            int gx0 = x0 - 4 + 4 * xg;
            float4 v = make_float4(0.f, 0.f, 0.f, 0.f);
            if ((unsigned)gy < 256u && (unsigned)gx0 <= 252u)
                v = *(const float4*)&input[((b * 32 + ci) * 256 + gy) * 256 + gx0];
            const int o = ci >> 3, c7 = ci & 7;
            float vv[4] = {v.x, v.y, v.z, v.w};
            #pragma unroll
            for (int m = 0; m < 4; ++m) {
                int u = 4 * xg + m - 3;        // gx = x0-1+u
                if ((unsigned)u < 18u) {
                    int slot = (o + (u >> 1)) & 3;
                    xlds[y * YS + u * 32 + slot * 8 + c7] =
                        (unsigned short)bf16_rne_bits(vv[m]);
                }
            }
        }
    }
    __syncthreads();

    // ---- compute: 3 kw-passes, each {6 weight frags, 10 row frags, 48 MFMA} ----
    f32x4 acc[8];
    #pragma unroll
    for (int i = 0; i < 8; ++i) acc[i] = (f32x4){0.f, 0.f, 0.f, 0.f};

    #pragma unroll 1
    for (int kw = 0; kw < 3; ++kw) {
        const int u = t + kw;                    // 0..17, always staged
        const int slot = (g + (u >> 1)) & 3;

        bf16x8 wf[3][2];
        const unsigned short* wb =
            Wk + (b * 9 * 2) * 1024 + f * 512 + t * 32 + g * 8;
        #pragma unroll
        for (int kh = 0; kh < 3; ++kh) {
            wf[kh][0] = *(const bf16x8*)(wb + ((kh * 3 + kw) * 2 + 0) * 1024);
            wf[kh][1] = *(const bf16x8*)(wb + ((kh * 3 + kw) * 2 + 1) * 1024);
        }

        bf16x8 xv[10];
        #pragma unroll
        for (int y = 0; y < 10; ++y)
            xv[y] = *(const bf16x8*)&xlds[(rbase + y) * YS + u * 32 + slot * 8];

        #pragma unroll
        for (int kh = 0; kh < 3; ++kh)
            #pragma unroll
            for (int i = 0; i < 8; ++i) {
                acc[i] = __builtin_amdgcn_mfma_f32_16x16x32_bf16(
                    wf[kh][0], xv[i + kh], acc[i], 0, 0, 0);
                acc[i] = __builtin_amdgcn_mfma_f32_16x16x32_bf16(
                    wf[kh][1], xv[i + kh], acc[i], 0, 0, 0);
            }
    }

    // ---- epilogue: stores (fp32 or bf16) + stats ----
    float s_[4] = {0.f, 0.f, 0.f, 0.f}, q_[4] = {0.f, 0.f, 0.f, 0.f};
    #pragma unroll
    for (int i = 0; i < 8; ++i) {
        const int gy = y0 + rbase + i;
        #pragma unroll
        for (int r = 0; r < 4; ++r) {
            float v = acc[i][r];
            const int off = (b * 32 + 16 * f + 4 * g + r) * 65536 + gy * 256 + x0 + t;
            if (bfout)
                bfout[off] = (unsigned short)bf16_rne_bits(v);
            else
                out[off] = v;
            s_[r] += v;
            q_[r] += v * v;
        }
    }
    #pragma unroll
    for (int r = 0; r < 4; ++r) {
        #pragma unroll
        for (int off = 1; off < 16; off <<= 1) {
            s_[r] += __shfl_xor(s_[r], off);
            q_[r] += __shfl_xor(q_[r], off);
        }
    }
    if (t == 0) {
        #pragma unroll
        for (int r = 0; r < 4; ++r)
            stats[wv * 32 + 16 * f + 4 * g + r] = make_float2(s_[r], q_[r]);
    }
    __syncthreads();
    if (tid < 32) {
        int w0 = (tid < 16) ? 0 : 1;            // waves 0/2 own co<16, 1/3 co>=16
        float2 a = stats[w0 * 32 + tid];
        float2 c = stats[(w0 + 2) * 32 + tid];
        partials[(b * 32 + tid) * NTILE + yt * NXT + xt] =
            make_float2(a.x + c.x, a.y + c.y);
    }
}

// ---------------- fold tile partials -> inv std ----------------
__global__ __launch_bounds__(256) void reduce_kernel(
    const float2* __restrict__ partials,
    float* __restrict__ inv_std) {
    int t = blockIdx.x * 256 + threadIdx.x;
    if (t >= BB * COUT) return;
    float s = 0.f, sq = 0.f;
    for (int k = 0; k < NTILE; ++k) {
        float2 p = partials[t * NTILE + k];
        s += p.x; sq += p.y;
    }
    const float N = 65536.f;
    float var = (sq - s * s / N) / (N - 1.f);   // unbiased (ddof=1)
    inv_std[t] = 1.0f / sqrtf(var);
}

// ---------------- scale: fp32 in-place (fallback) ----------------
__global__ __launch_bounds__(256) void scale_kernel(
    float4* __restrict__ out,
    const float* __restrict__ inv_std) {
    const int n4 = BB * COUT * HH * WW / 4;     // 8388608
    for (int i = blockIdx.x * 256 + threadIdx.x; i < n4; i += gridDim.x * 256) {
        float m = inv_std[i >> 14];
        float4 v = out[i];
        v.x *= m; v.y *= m; v.z *= m; v.w *= m;
        out[i] = v;
    }
}

// ---------------- scale: bf16 ws -> fp32 out ----------------
__global__ __launch_bounds__(256) void scale_bf16_kernel(
    const unsigned short* __restrict__ bf,
    const float* __restrict__ inv_std,
    float* __restrict__ out) {
    const int n8 = BB * COUT * HH * WW / 8;     // 4194304
    for (int i = blockIdx.x * 256 + threadIdx.x; i < n8; i += gridDim.x * 256) {
        float m = inv_std[i >> 13];             // (i*8)>>16
        u16x8 v = *(const u16x8*)&bf[i * 8];
        float4 a, c;
        a.x = __uint_as_float(((unsigned)v[0]) << 16) * m;
        a.y = __uint_as_float(((unsigned)v[1]) << 16) * m;
        a.z = __uint_as_float(((unsigned)v[2]) << 16) * m;
        a.w = __uint_as_float(((unsigned)v[3]) << 16) * m;
        c.x = __uint_as_float(((unsigned)v[4]) << 16) * m;
        c.y = __uint_as_float(((unsigned)v[5]) << 16) * m;
        c.z = __uint_as_float(((unsigned)v[6]) << 16) * m;
        c.w = __uint_as_float(((unsigned)v[7]) << 16) * m;
        *(float4*)&out[i * 8]     = a;
        *(float4*)&out[i * 8 + 4] = c;
    }
}

extern "C" void kernel_launch(void* const* d_in, const int* in_sizes, int n_in,
                              void* d_out, int out_size, void* d_ws, size_t ws_size,
                              hipStream_t stream) {
    const float* input      = (const float*)d_in[0];
    const float* style      = (const float*)d_in[1];
    const float* weight     = (const float*)d_in[2];
    const float* mod_weight = (const float*)d_in[3];
    const float* mod_bias   = (const float*)d_in[4];
    float* out = (float*)d_out;
    char*  ws  = (char*)d_ws;

    float*          s        = (float*)ws;                        // 2048 B
    unsigned short* Wk       = (unsigned short*)(ws + 2048);      // 589824 B
    float2*         partials = (float2*)(ws + 2048 + 589824);     // 1048576 B
    float*          inv      = (float*)(ws + 2048 + 589824 + 1048576);  // 2048 B
    const size_t    bf_off   = 2048 + 589824 + 1048576 + 2048;
    const size_t    bf_bytes = (size_t)BB * COUT * HH * WW * 2;   // 67108864
    const bool      use_bf16 = ws_size >= bf_off + bf_bytes;
    unsigned short* bfout    = use_bf16 ? (unsigned short*)(ws + bf_off) : nullptr;

    prep_s_kernel<<<1, 512, 0, stream>>>(style, mod_weight, mod_bias, s);
    prep_w_kernel<<<(BB * COUT * CIN * 9 + 255) / 256, 256, 0, stream>>>(
        weight, s, Wk);

    conv_mfma_kernel<<<4096, 256, 0, stream>>>(input, Wk, out, bfout, partials);

    reduce_kernel<<<2, 256, 0, stream>>>(partials, inv);
    if (use_bf16)
        scale_bf16_kernel<<<2048, 256, 0, stream>>>(bfout, inv, out);
    else
        scale_kernel<<<2048, 256, 0, stream>>>((float4*)out, inv);
}